// Round 2
// baseline (379.142 us; speedup 1.0000x reference)
//
#include <hip/hip_runtime.h>
#include <hip/hip_bf16.h>

// Nat2D neighborhood attention, MI355X gfx950.
// Device ABI: f32 inputs, f32 output (reference dtypes). bf16 MFMA internally.
// Pipeline: [cast x,Wqkv,Wproj -> bf16] -> [gemm QKV (f32 out)] ->
//           [natten per (pixel,head) wave] -> [gemm proj -> f32 d_out]

typedef __attribute__((ext_vector_type(4))) float f32x4;
typedef __attribute__((ext_vector_type(8))) short bf16x8;
typedef __attribute__((ext_vector_type(4))) short s16x4;

#define HEADS 8
#define HEAD_DIM 64
#define DIM 512
#define KW 7
#define HH 80
#define WW 80
#define NPIX (HH * WW)

__device__ inline unsigned short f2bf(float f) {
    union { __hip_bfloat16 b; unsigned short u; } cvt;
    cvt.b = __float2bfloat16(f);
    return cvt.u;
}

__device__ inline void storeC(float* p, float v) { *p = v; }
__device__ inline void storeC(__hip_bfloat16* p, float v) { *p = __float2bfloat16(v); }
__device__ inline float loadF(const float* p) { return *p; }
__device__ inline float loadF(const __hip_bfloat16* p) { return __bfloat162float(*p); }

// f32 -> bf16 elementwise, 4 elems/thread. n4 = n/4.
__global__ __launch_bounds__(256) void cast_f32_bf16(
    const float* __restrict__ in, __hip_bfloat16* __restrict__ out, int n4)
{
    const int i = blockIdx.x * 256 + threadIdx.x;
    if (i >= n4) return;
    f32x4 v = reinterpret_cast<const f32x4*>(in)[i];
    s16x4 r;
#pragma unroll
    for (int j = 0; j < 4; ++j) r[j] = (short)f2bf(v[j]);
    reinterpret_cast<s16x4*>(out)[i] = r;
}

// C[m,n] = sum_k A[m,k] * W[n,k] + bias[n]
// A: M x K bf16 row-major, W: N x K bf16 row-major (A @ W^T).
// Block: 256 threads = 4 waves; each wave computes a 64x64 C tile.
// grid.x = N/256, grid.y = M/64. Requires K % 32 == 0, M % 64 == 0, N % 256 == 0.
template <typename CT>
__global__ __launch_bounds__(256) void gemm_bt_bias(
    const __hip_bfloat16* __restrict__ A,
    const __hip_bfloat16* __restrict__ W,
    const float* __restrict__ bias,
    CT* __restrict__ C,
    int M, int N, int K)
{
    const int lane = threadIdx.x & 63;
    const int wv = threadIdx.x >> 6;
    const int r0 = blockIdx.y * 64;
    const int c0 = blockIdx.x * 256 + wv * 64;
    const int rf = lane & 15;   // row (A) / col (W) within fragment
    const int kg = lane >> 4;   // k-group (0..3), 8 consecutive k each

    f32x4 acc[4][4] = {};

    for (int kb = 0; kb < K; kb += 32) {
        const int kbase = kb + kg * 8;
        bf16x8 af[4], wf[4];
#pragma unroll
        for (int i = 0; i < 4; ++i)
            af[i] = *reinterpret_cast<const bf16x8*>(A + (size_t)(r0 + i * 16 + rf) * K + kbase);
#pragma unroll
        for (int i = 0; i < 4; ++i)
            wf[i] = *reinterpret_cast<const bf16x8*>(W + (size_t)(c0 + i * 16 + rf) * K + kbase);
#pragma unroll
        for (int i = 0; i < 4; ++i)
#pragma unroll
            for (int j = 0; j < 4; ++j)
                acc[i][j] = __builtin_amdgcn_mfma_f32_16x16x32_bf16(af[i], wf[j], acc[i][j], 0, 0, 0);
    }

    // C/D layout: col = lane&15, row = (lane>>4)*4 + reg  [m89-verified]
#pragma unroll
    for (int j = 0; j < 4; ++j) {
        const int col = c0 + j * 16 + rf;
        const float bcol = bias[col];
#pragma unroll
        for (int i = 0; i < 4; ++i) {
#pragma unroll
            for (int r = 0; r < 4; ++r) {
                const int row = r0 + i * 16 + kg * 4 + r;
                storeC(C + (size_t)row * N + col, acc[i][j][r] + bcol);
            }
        }
    }
}

// One wave per (pixel, head). lane = head dim (0..63).
// qkv: NPIX x 1536 (q at col h*64+d, k at +512, v at +1024), type QT.
// rpb: HEADS x 13 x 13 f32. aout: NPIX x 512 bf16 (head-major channels).
template <typename QT>
__global__ __launch_bounds__(256) void natten(
    const QT* __restrict__ qkv,
    const float* __restrict__ rpb,
    __hip_bfloat16* __restrict__ aout)
{
    __shared__ float s_w[4][64];
    const int lane = threadIdx.x & 63;
    const int wv = threadIdx.x >> 6;
    const int unit = blockIdx.x * 4 + wv;    // 0 .. NPIX*HEADS-1
    const int h = unit & 7;
    const int p = unit >> 3;
    const int pi = p / WW;
    const int pj = p - pi * WW;
    int si = pi - 3; si = si < 0 ? 0 : si; si = si > (HH - KW) ? (HH - KW) : si;
    int sj = pj - 3; sj = sj < 0 ? 0 : sj; sj = sj > (WW - KW) ? (WW - KW) : sj;
    const int oh = si - pi + 6;  // off_h[pi,a] = oh + a
    const int ow = sj - pj + 6;

    const float qd = loadF(qkv + (size_t)p * 1536 + h * 64 + lane);

    // Phase 1: 49 logits (q.k * 1/8 + bias), lane0 writes to LDS
#pragma unroll
    for (int a = 0; a < KW; ++a) {
        for (int c = 0; c < KW; ++c) {
            const int pn = (si + a) * WW + (sj + c);
            float v = qd * loadF(qkv + (size_t)pn * 1536 + 512 + h * 64 + lane);
#pragma unroll
            for (int off = 32; off > 0; off >>= 1) v += __shfl_xor(v, off, 64);
            if (lane == 0) {
                s_w[wv][a * KW + c] = 0.125f * v + rpb[h * 169 + (oh + a) * 13 + (ow + c)];
            }
        }
    }
    __syncthreads();

    // Phase 2: softmax over 49 logits -> normalized weights in LDS
    {
        float l = (lane < 49) ? s_w[wv][lane] : -1e30f;
        float m = l;
#pragma unroll
        for (int off = 32; off > 0; off >>= 1) m = fmaxf(m, __shfl_xor(m, off, 64));
        float e = (lane < 49) ? __expf(l - m) : 0.f;
        float s = e;
#pragma unroll
        for (int off = 32; off > 0; off >>= 1) s += __shfl_xor(s, off, 64);
        if (lane < 49) s_w[wv][lane] = e / s;
    }
    __syncthreads();

    // Phase 3: out[d] = sum_j w_j * v[nb_j, d]
    float o = 0.f;
#pragma unroll
    for (int a = 0; a < KW; ++a) {
        for (int c = 0; c < KW; ++c) {
            const int pn = (si + a) * WW + (sj + c);
            const float w = s_w[wv][a * KW + c];
            o += w * loadF(qkv + (size_t)pn * 1536 + 1024 + h * 64 + lane);
        }
    }
    aout[(size_t)p * 512 + h * 64 + lane] = __float2bfloat16(o);
}

extern "C" void kernel_launch(void* const* d_in, const int* in_sizes, int n_in,
                              void* d_out, int out_size, void* d_ws, size_t ws_size,
                              hipStream_t stream) {
    const float* x      = (const float*)d_in[0];
    const float* qkv_w  = (const float*)d_in[1];
    const float* qkv_b  = (const float*)d_in[2];
    const float* rpb    = (const float*)d_in[3];
    const float* proj_w = (const float*)d_in[4];
    const float* proj_b = (const float*)d_in[5];
    float* out = (float*)d_out;

    const size_t n_x = (size_t)NPIX * DIM;          // 3,276,800
    const size_t n_wqkv = (size_t)3 * DIM * DIM;    // 786,432
    const size_t n_wproj = (size_t)DIM * DIM;       // 262,144
    const size_t n_qkv = (size_t)NPIX * 3 * DIM;    // 9,830,400

    // ws layout
    char* wsb = (char*)d_ws;
    __hip_bfloat16* xb    = (__hip_bfloat16*)wsb;                       // 6,553,600 B
    __hip_bfloat16* wqkv  = (__hip_bfloat16*)(wsb + 6553600);           // 1,572,864 B
    __hip_bfloat16* wproj = (__hip_bfloat16*)(wsb + 8126464);           //   524,288 B
    char* qkv_base        = wsb + 8650752;

    const size_t need_f32 = 8650752 + n_qkv * 4 + n_x * 2;  // 54,525,952

    dim3 blk(256);
    // casts
    cast_f32_bf16<<<dim3((unsigned)(n_x / 4 / 256)), blk, 0, stream>>>(x, xb, (int)(n_x / 4));
    cast_f32_bf16<<<dim3((unsigned)(n_wqkv / 4 / 256)), blk, 0, stream>>>(qkv_w, wqkv, (int)(n_wqkv / 4));
    cast_f32_bf16<<<dim3((unsigned)(n_wproj / 4 / 256)), blk, 0, stream>>>(proj_w, wproj, (int)(n_wproj / 4));

    if (ws_size >= need_f32) {
        float* qkv = (float*)qkv_base;
        __hip_bfloat16* aout = (__hip_bfloat16*)(qkv_base + n_qkv * 4);
        gemm_bt_bias<float><<<dim3((3 * DIM) / 256, NPIX / 64), blk, 0, stream>>>(
            xb, wqkv, qkv_b, qkv, NPIX, 3 * DIM, DIM);
        natten<float><<<dim3(NPIX * HEADS / 4), blk, 0, stream>>>(qkv, rpb, aout);
        gemm_bt_bias<float><<<dim3(DIM / 256, NPIX / 64), blk, 0, stream>>>(
            aout, wproj, proj_b, out, NPIX, DIM, DIM);
    } else {
        __hip_bfloat16* qkv = (__hip_bfloat16*)qkv_base;
        __hip_bfloat16* aout = (__hip_bfloat16*)(qkv_base + n_qkv * 2);
        gemm_bt_bias<__hip_bfloat16><<<dim3((3 * DIM) / 256, NPIX / 64), blk, 0, stream>>>(
            xb, wqkv, qkv_b, qkv, NPIX, 3 * DIM, DIM);
        natten<__hip_bfloat16><<<dim3(NPIX * HEADS / 4), blk, 0, stream>>>(qkv, rpb, aout);
        gemm_bt_bias<float><<<dim3(DIM / 256, NPIX / 64), blk, 0, stream>>>(
            aout, wproj, proj_b, out, NPIX, DIM, DIM);
    }
}

// Round 3
// 233.812 us; speedup vs baseline: 1.6216x; 1.6216x over previous
//
#include <hip/hip_runtime.h>
#include <hip/hip_bf16.h>

// Nat2D neighborhood attention, MI355X gfx950.
// Device ABI: f32 inputs, f32 output. bf16 MFMA for GEMMs, f32 natten.
// Pipeline: [cast x,Wqkv,Wproj -> bf16] -> [gemm QKV (f32 out)] ->
//           [natten: 4-neighbor/iter group-parallel] -> [gemm proj -> f32 out]

typedef __attribute__((ext_vector_type(4))) float f32x4;
typedef __attribute__((ext_vector_type(8))) short bf16x8;
typedef __attribute__((ext_vector_type(4))) short s16x4;

#define HEADS 8
#define HEAD_DIM 64
#define DIM 512
#define KW 7
#define HH 80
#define WW 80
#define NPIX (HH * WW)

__device__ inline unsigned short f2bf(float f) {
    union { __hip_bfloat16 b; unsigned short u; } cvt;
    cvt.b = __float2bfloat16(f);
    return cvt.u;
}

__device__ inline void storeC(float* p, float v) { *p = v; }
__device__ inline void storeC(__hip_bfloat16* p, float v) { *p = __float2bfloat16(v); }

__device__ inline f32x4 load4(const float* p) {
    return *reinterpret_cast<const f32x4*>(p);
}
__device__ inline f32x4 load4(const __hip_bfloat16* p) {
    s16x4 r = *reinterpret_cast<const s16x4*>(p);
    f32x4 o;
#pragma unroll
    for (int j = 0; j < 4; ++j) {
        union { float f; unsigned u; } c; c.u = ((unsigned)(unsigned short)r[j]) << 16;
        o[j] = c.f;
    }
    return o;
}

// f32 -> bf16 elementwise, 4 elems/thread. n4 = n/4.
__global__ __launch_bounds__(256) void cast_f32_bf16(
    const float* __restrict__ in, __hip_bfloat16* __restrict__ out, int n4)
{
    const int i = blockIdx.x * 256 + threadIdx.x;
    if (i >= n4) return;
    f32x4 v = reinterpret_cast<const f32x4*>(in)[i];
    s16x4 r;
#pragma unroll
    for (int j = 0; j < 4; ++j) r[j] = (short)f2bf(v[j]);
    reinterpret_cast<s16x4*>(out)[i] = r;
}

// C[m,n] = sum_k A[m,k] * W[n,k] + bias[n]
// A: M x K bf16 row-major, W: N x K bf16 row-major (A @ W^T).
// Block: 256 threads = 4 waves; each wave computes a 64x64 C tile.
template <typename CT>
__global__ __launch_bounds__(256) void gemm_bt_bias(
    const __hip_bfloat16* __restrict__ A,
    const __hip_bfloat16* __restrict__ W,
    const float* __restrict__ bias,
    CT* __restrict__ C,
    int M, int N, int K)
{
    const int lane = threadIdx.x & 63;
    const int wv = threadIdx.x >> 6;
    const int r0 = blockIdx.y * 64;
    const int c0 = blockIdx.x * 256 + wv * 64;
    const int rf = lane & 15;
    const int kg = lane >> 4;

    f32x4 acc[4][4] = {};

    for (int kb = 0; kb < K; kb += 32) {
        const int kbase = kb + kg * 8;
        bf16x8 af[4], wf[4];
#pragma unroll
        for (int i = 0; i < 4; ++i)
            af[i] = *reinterpret_cast<const bf16x8*>(A + (size_t)(r0 + i * 16 + rf) * K + kbase);
#pragma unroll
        for (int i = 0; i < 4; ++i)
            wf[i] = *reinterpret_cast<const bf16x8*>(W + (size_t)(c0 + i * 16 + rf) * K + kbase);
#pragma unroll
        for (int i = 0; i < 4; ++i)
#pragma unroll
            for (int j = 0; j < 4; ++j)
                acc[i][j] = __builtin_amdgcn_mfma_f32_16x16x32_bf16(af[i], wf[j], acc[i][j], 0, 0, 0);
    }

    // C/D layout: col = lane&15, row = (lane>>4)*4 + reg  [m89-verified]
#pragma unroll
    for (int j = 0; j < 4; ++j) {
        const int col = c0 + j * 16 + rf;
        const float bcol = bias[col];
#pragma unroll
        for (int i = 0; i < 4; ++i) {
#pragma unroll
            for (int r = 0; r < 4; ++r) {
                const int row = r0 + i * 16 + kg * 4 + r;
                storeC(C + (size_t)row * N + col, acc[i][j][r] + bcol);
            }
        }
    }
}

// One wave per (pixel, head). Lane = (g = lane>>4: neighbor sub-slot) x
// (t = lane&15: 4 dims each). unit = h*NPIX + p so adjacent waves share head
// and neighboring pixels (L1/L2 locality).
// qkv: NPIX x 1536 (q at h*64, k at +512, v at +1024), type QT.
// rpb: HEADS x 13 x 13 f32. aout: NPIX x 512 bf16.
template <typename QT>
__global__ __launch_bounds__(256) void natten(
    const QT* __restrict__ qkv,
    const float* __restrict__ rpb,
    __hip_bfloat16* __restrict__ aout)
{
    __shared__ float s_w[4][64];
    const int lane = threadIdx.x & 63;
    const int wv = threadIdx.x >> 6;
    const int g = lane >> 4;       // neighbor sub-slot 0..3
    const int t = lane & 15;       // dim group: dims t*4 .. t*4+3
    const int unit = blockIdx.x * 4 + wv;   // 0 .. NPIX*HEADS-1
    const int h = unit / NPIX;
    const int p = unit - h * NPIX;
    const int pi = p / WW;
    const int pj = p - pi * WW;
    int si = pi - 3; si = si < 0 ? 0 : si; si = si > (HH - KW) ? (HH - KW) : si;
    int sj = pj - 3; sj = sj < 0 ? 0 : sj; sj = sj > (WW - KW) ? (WW - KW) : sj;
    const int oh = si - pi + 6;
    const int ow = sj - pj + 6;

    const QT* qkv_h = qkv + h * 64;
    const f32x4 qf = load4(qkv_h + (size_t)p * 1536 + t * 4);

    // Phase 1: 49 logits, 4 per iteration (one per 16-lane group).
#pragma unroll
    for (int it = 0; it < 13; ++it) {
        const int nb = it * 4 + g;
        const int nbc = nb > 48 ? 48 : nb;
        const int a = nbc / KW;
        const int c = nbc - a * KW;
        const int pn = (si + a) * WW + (sj + c);
        const f32x4 kf = load4(qkv_h + (size_t)pn * 1536 + 512 + t * 4);
        float s = qf[0] * kf[0] + qf[1] * kf[1] + qf[2] * kf[2] + qf[3] * kf[3];
#pragma unroll
        for (int off = 1; off < 16; off <<= 1) s += __shfl_xor(s, off, 64);
        if (t == 0 && nb < 49)
            s_w[wv][nb] = 0.125f * s + rpb[h * 169 + (oh + a) * 13 + (ow + c)];
    }
    __syncthreads();

    // Phase 2: softmax over 49 logits.
    {
        float l = (lane < 49) ? s_w[wv][lane] : -1e30f;
        float m = l;
#pragma unroll
        for (int off = 32; off > 0; off >>= 1) m = fmaxf(m, __shfl_xor(m, off, 64));
        float e = (lane < 49) ? __expf(l - m) : 0.f;
        float s = e;
#pragma unroll
        for (int off = 32; off > 0; off >>= 1) s += __shfl_xor(s, off, 64);
        if (lane < 49) s_w[wv][lane] = e / s;
    }
    __syncthreads();

    // Phase 3: out[d] = sum_nb w_nb * v[pn_nb][d], 4 neighbors/iter.
    f32x4 o = {0.f, 0.f, 0.f, 0.f};
#pragma unroll
    for (int it = 0; it < 13; ++it) {
        const int nb = it * 4 + g;
        const int nbc = nb > 48 ? 48 : nb;
        const int a = nbc / KW;
        const int c = nbc - a * KW;
        const int pn = (si + a) * WW + (sj + c);
        const float w = (nb < 49) ? s_w[wv][nb] : 0.f;
        const f32x4 vf = load4(qkv_h + (size_t)pn * 1536 + 1024 + t * 4);
#pragma unroll
        for (int j = 0; j < 4; ++j) o[j] += w * vf[j];
    }
    // cross-group reduce (xor 16, 32)
#pragma unroll
    for (int j = 0; j < 4; ++j) {
        o[j] += __shfl_xor(o[j], 16, 64);
        o[j] += __shfl_xor(o[j], 32, 64);
    }
    if (g == 0) {
        s16x4 r;
#pragma unroll
        for (int j = 0; j < 4; ++j) r[j] = (short)f2bf(o[j]);
        *reinterpret_cast<s16x4*>(aout + (size_t)p * 512 + h * 64 + t * 4) = r;
    }
}

extern "C" void kernel_launch(void* const* d_in, const int* in_sizes, int n_in,
                              void* d_out, int out_size, void* d_ws, size_t ws_size,
                              hipStream_t stream) {
    const float* x      = (const float*)d_in[0];
    const float* qkv_w  = (const float*)d_in[1];
    const float* qkv_b  = (const float*)d_in[2];
    const float* rpb    = (const float*)d_in[3];
    const float* proj_w = (const float*)d_in[4];
    const float* proj_b = (const float*)d_in[5];
    float* out = (float*)d_out;

    const size_t n_x = (size_t)NPIX * DIM;          // 3,276,800
    const size_t n_wqkv = (size_t)3 * DIM * DIM;    // 786,432
    const size_t n_wproj = (size_t)DIM * DIM;       // 262,144
    const size_t n_qkv = (size_t)NPIX * 3 * DIM;    // 9,830,400

    char* wsb = (char*)d_ws;
    __hip_bfloat16* xb    = (__hip_bfloat16*)wsb;
    __hip_bfloat16* wqkv  = (__hip_bfloat16*)(wsb + 6553600);
    __hip_bfloat16* wproj = (__hip_bfloat16*)(wsb + 8126464);
    char* qkv_base        = wsb + 8650752;

    const size_t need_f32 = 8650752 + n_qkv * 4 + n_x * 2;  // 54,525,952

    dim3 blk(256);
    cast_f32_bf16<<<dim3((unsigned)(n_x / 4 / 256)), blk, 0, stream>>>(x, xb, (int)(n_x / 4));
    cast_f32_bf16<<<dim3((unsigned)(n_wqkv / 4 / 256)), blk, 0, stream>>>(qkv_w, wqkv, (int)(n_wqkv / 4));
    cast_f32_bf16<<<dim3((unsigned)(n_wproj / 4 / 256)), blk, 0, stream>>>(proj_w, wproj, (int)(n_wproj / 4));

    if (ws_size >= need_f32) {
        float* qkv = (float*)qkv_base;
        __hip_bfloat16* aout = (__hip_bfloat16*)(qkv_base + n_qkv * 4);
        gemm_bt_bias<float><<<dim3((3 * DIM) / 256, NPIX / 64), blk, 0, stream>>>(
            xb, wqkv, qkv_b, qkv, NPIX, 3 * DIM, DIM);
        natten<float><<<dim3(NPIX * HEADS / 4), blk, 0, stream>>>(qkv, rpb, aout);
        gemm_bt_bias<float><<<dim3(DIM / 256, NPIX / 64), blk, 0, stream>>>(
            aout, wproj, proj_b, out, NPIX, DIM, DIM);
    } else {
        __hip_bfloat16* qkv = (__hip_bfloat16*)qkv_base;
        __hip_bfloat16* aout = (__hip_bfloat16*)(qkv_base + n_qkv * 2);
        gemm_bt_bias<__hip_bfloat16><<<dim3((3 * DIM) / 256, NPIX / 64), blk, 0, stream>>>(
            xb, wqkv, qkv_b, qkv, NPIX, 3 * DIM, DIM);
        natten<__hip_bfloat16><<<dim3(NPIX * HEADS / 4), blk, 0, stream>>>(qkv, rpb, aout);
        gemm_bt_bias<float><<<dim3(DIM / 256, NPIX / 64), blk, 0, stream>>>(
            aout, wproj, proj_b, out, NPIX, DIM, DIM);
    }
}

// Round 5
// 185.715 us; speedup vs baseline: 2.0415x; 1.2590x over previous
//
#include <hip/hip_runtime.h>
#include <hip/hip_bf16.h>

// Nat2D neighborhood attention, MI355X gfx950.
// Device ABI: f32 inputs, f32 output. bf16 MFMA for GEMMs, bf16 qkv intermediate.
// Pipeline: [cast x,Wqkv,Wproj -> bf16] -> [gemm QKV -> bf16 qkv] ->
//           [natten_tiled: 8x8 pixel tile x head, K/V halo in LDS] ->
//           [gemm proj -> f32 out]

typedef __attribute__((ext_vector_type(4))) float f32x4;
typedef __attribute__((ext_vector_type(8))) short bf16x8;
typedef __attribute__((ext_vector_type(4))) short s16x4;

#define HEADS 8
#define HEAD_DIM 64
#define DIM 512
#define KW 7
#define HH 80
#define WW 80
#define NPIX (HH * WW)

__device__ inline unsigned short f2bf(float f) {
    union { __hip_bfloat16 b; unsigned short u; } cvt;
    cvt.b = __float2bfloat16(f);
    return cvt.u;
}
__device__ inline float bf2f(short s) {
    union { float f; unsigned u; } c;
    c.u = ((unsigned)(unsigned short)s) << 16;
    return c.f;
}

__device__ inline void storeC(float* p, float v) { *p = v; }
__device__ inline void storeC(__hip_bfloat16* p, float v) { *p = __float2bfloat16(v); }

// f32 -> bf16 elementwise, 4 elems/thread. n4 = n/4.
__global__ __launch_bounds__(256) void cast_f32_bf16(
    const float* __restrict__ in, __hip_bfloat16* __restrict__ out, int n4)
{
    const int i = blockIdx.x * 256 + threadIdx.x;
    if (i >= n4) return;
    f32x4 v = reinterpret_cast<const f32x4*>(in)[i];
    s16x4 r;
#pragma unroll
    for (int j = 0; j < 4; ++j) r[j] = (short)f2bf(v[j]);
    reinterpret_cast<s16x4*>(out)[i] = r;
}

// C[m,n] = sum_k A[m,k] * W[n,k] + bias[n]
// A: M x K bf16 row-major, W: N x K bf16 row-major (A @ W^T).
// Block: 256 threads = 4 waves; each wave computes a 64x64 C tile.
template <typename CT>
__global__ __launch_bounds__(256) void gemm_bt_bias(
    const __hip_bfloat16* __restrict__ A,
    const __hip_bfloat16* __restrict__ W,
    const float* __restrict__ bias,
    CT* __restrict__ C,
    int M, int N, int K)
{
    const int lane = threadIdx.x & 63;
    const int wv = threadIdx.x >> 6;
    const int r0 = blockIdx.y * 64;
    const int c0 = blockIdx.x * 256 + wv * 64;
    const int rf = lane & 15;
    const int kg = lane >> 4;

    f32x4 acc[4][4] = {};

    for (int kb = 0; kb < K; kb += 32) {
        const int kbase = kb + kg * 8;
        bf16x8 af[4], wf[4];
#pragma unroll
        for (int i = 0; i < 4; ++i)
            af[i] = *reinterpret_cast<const bf16x8*>(A + (size_t)(r0 + i * 16 + rf) * K + kbase);
#pragma unroll
        for (int i = 0; i < 4; ++i)
            wf[i] = *reinterpret_cast<const bf16x8*>(W + (size_t)(c0 + i * 16 + rf) * K + kbase);
#pragma unroll
        for (int i = 0; i < 4; ++i)
#pragma unroll
            for (int j = 0; j < 4; ++j)
                acc[i][j] = __builtin_amdgcn_mfma_f32_16x16x32_bf16(af[i], wf[j], acc[i][j], 0, 0, 0);
    }

    // C/D layout: col = lane&15, row = (lane>>4)*4 + reg  [m89-verified]
#pragma unroll
    for (int j = 0; j < 4; ++j) {
        const int col = c0 + j * 16 + rf;
        const float bcol = bias[col];
#pragma unroll
        for (int i = 0; i < 4; ++i) {
#pragma unroll
            for (int r = 0; r < 4; ++r) {
                const int row = r0 + i * 16 + kg * 4 + r;
                storeC(C + (size_t)row * N + col, acc[i][j][r] + bcol);
            }
        }
    }
}

// Tiled natten: block = (8x8 pixel tile) x (one head). 256 threads = 4 waves.
// Stage K/V halo (14x14 rows x 64 dims, bf16, stride 72) + rpb slice in LDS.
// Thread (p, g): pixel p (0..63), dim-quarter g (0..3) -> dims g*16..g*16+15.
// qkv: NPIX x 1536 bf16 (q | k | v each 512). aout: NPIX x 512 bf16.
__global__ __launch_bounds__(256) void natten_tiled(
    const __hip_bfloat16* __restrict__ qkv,
    const float* __restrict__ rpb,
    __hip_bfloat16* __restrict__ aout)
{
    __shared__ short sK[196][72];   // 28224 B, stride 144 B (16B-aligned)
    __shared__ short sV[196][72];   // 28224 B
    __shared__ float sW[64][52];    // 13312 B, per-pixel 49 logits/weights
    __shared__ float sB[169];       // rpb[h] slice

    const int tid = threadIdx.x;
    const int h = blockIdx.y;
    const int ti = blockIdx.x / 10;
    const int tj = blockIdx.x - ti * 10;
    const int R0 = ti * 8 - 3;
    const int C0 = tj * 8 - 3;

    if (tid < 169) sB[tid] = rpb[h * 169 + tid];

    // Stage K,V halo: 196 slots x 8 chunks of 16B = 1568 tasks.
#pragma unroll
    for (int it = 0; it < 7; ++it) {
        const int task = it * 256 + tid;
        if (task < 1568) {
            const int slot = task >> 3;
            const int ch = task & 7;
            const int r = slot / 14;
            const int c = slot - r * 14;
            int gi = R0 + r; gi = gi < 0 ? 0 : (gi > 79 ? 79 : gi);
            int gj = C0 + c; gj = gj < 0 ? 0 : (gj > 79 ? 79 : gj);
            const __hip_bfloat16* src =
                qkv + ((size_t)(gi * WW + gj) * 1536 + 512 + h * 64 + ch * 8);
            bf16x8 kv = *reinterpret_cast<const bf16x8*>(src);
            bf16x8 vv = *reinterpret_cast<const bf16x8*>(src + 512);
            *reinterpret_cast<bf16x8*>(&sK[slot][ch * 8]) = kv;
            *reinterpret_cast<bf16x8*>(&sV[slot][ch * 8]) = vv;
        }
    }
    __syncthreads();

    const int lane = tid & 63;
    const int wv = tid >> 6;
    const int p = wv * 16 + (lane >> 2);   // tile-local pixel 0..63
    const int g = lane & 3;                // dim quarter
    const int pi_l = p >> 3, pj_l = p & 7;
    const int pi = ti * 8 + pi_l, pj = tj * 8 + pj_l;
    int si = pi - 3; si = si < 0 ? 0 : (si > (HH - KW) ? (HH - KW) : si);
    int sj = pj - 3; sj = sj < 0 ? 0 : (sj > (WW - KW) ? (WW - KW) : sj);
    const int si_l = si - R0;              // halo-local window start row
    const int sj_l = sj - C0;
    const int oh = si - pi + 6;
    const int ow = sj - pj + 6;

    // q fragment (16 dims) with 1/8 scale folded in
    float qf[16];
    {
        const __hip_bfloat16* qsrc =
            qkv + ((size_t)(pi * WW + pj) * 1536 + h * 64 + g * 16);
        bf16x8 q0 = *reinterpret_cast<const bf16x8*>(qsrc);
        bf16x8 q1 = *reinterpret_cast<const bf16x8*>(qsrc + 8);
#pragma unroll
        for (int j = 0; j < 8; ++j) {
            qf[j] = 0.125f * bf2f(q0[j]);
            qf[8 + j] = 0.125f * bf2f(q1[j]);
        }
    }

    // Phase 1: 49 logits per pixel
    for (int a = 0; a < KW; ++a) {
        const int rbase = (si_l + a) * 14 + sj_l;
        const float* brow = &sB[(oh + a) * 13 + ow];
#pragma unroll
        for (int c = 0; c < KW; ++c) {
            const int slot = rbase + c;
            bf16x8 k0 = *reinterpret_cast<const bf16x8*>(&sK[slot][g * 16]);
            bf16x8 k1 = *reinterpret_cast<const bf16x8*>(&sK[slot][g * 16 + 8]);
            float d = 0.f;
#pragma unroll
            for (int j = 0; j < 8; ++j) d += qf[j] * bf2f(k0[j]);
#pragma unroll
            for (int j = 0; j < 8; ++j) d += qf[8 + j] * bf2f(k1[j]);
            d += __shfl_xor(d, 1, 64);
            d += __shfl_xor(d, 2, 64);
            if (g == 0) sW[p][a * KW + c] = d + brow[c];
        }
    }
    // sW[p] written and read only by this wave's own lanes -> no barrier needed.

    // Phase 2: softmax over 49 (all 4 g-lanes redundantly; g==0 writes back exp)
    float m = -1e30f;
    for (int i = 0; i < 49; ++i) m = fmaxf(m, sW[p][i]);
    float s = 0.f;
    for (int i = 0; i < 49; ++i) {
        const float e = __expf(sW[p][i] - m);
        s += e;
        if (g == 0) sW[p][i] = e;
    }
    const float rs = 1.0f / s;

    // Phase 3: o[d] = (1/s) * sum_nb e_nb * v[nb][d]
    float o[16];
#pragma unroll
    for (int j = 0; j < 16; ++j) o[j] = 0.f;
    for (int a = 0; a < KW; ++a) {
        const int rbase = (si_l + a) * 14 + sj_l;
#pragma unroll
        for (int c = 0; c < KW; ++c) {
            const int slot = rbase + c;
            const float w = sW[p][a * KW + c];
            bf16x8 v0 = *reinterpret_cast<const bf16x8*>(&sV[slot][g * 16]);
            bf16x8 v1 = *reinterpret_cast<const bf16x8*>(&sV[slot][g * 16 + 8]);
#pragma unroll
            for (int j = 0; j < 8; ++j) o[j] += w * bf2f(v0[j]);
#pragma unroll
            for (int j = 0; j < 8; ++j) o[8 + j] += w * bf2f(v1[j]);
        }
    }

    bf16x8 r0v, r1v;
#pragma unroll
    for (int j = 0; j < 8; ++j) {
        r0v[j] = (short)f2bf(o[j] * rs);
        r1v[j] = (short)f2bf(o[8 + j] * rs);
    }
    __hip_bfloat16* dst = aout + ((size_t)(pi * WW + pj) * 512 + h * 64 + g * 16);
    *reinterpret_cast<bf16x8*>(dst) = r0v;
    *reinterpret_cast<bf16x8*>(dst + 8) = r1v;
}

extern "C" void kernel_launch(void* const* d_in, const int* in_sizes, int n_in,
                              void* d_out, int out_size, void* d_ws, size_t ws_size,
                              hipStream_t stream) {
    const float* x      = (const float*)d_in[0];
    const float* qkv_w  = (const float*)d_in[1];
    const float* qkv_b  = (const float*)d_in[2];
    const float* rpb    = (const float*)d_in[3];
    const float* proj_w = (const float*)d_in[4];
    const float* proj_b = (const float*)d_in[5];
    float* out = (float*)d_out;

    const size_t n_x = (size_t)NPIX * DIM;          // 3,276,800
    const size_t n_wqkv = (size_t)3 * DIM * DIM;    // 786,432
    const size_t n_wproj = (size_t)DIM * DIM;       // 262,144
    const size_t n_qkv = (size_t)NPIX * 3 * DIM;    // 9,830,400

    // ws layout (all bf16): xb | wqkv | wproj | qkv | aout  = 34.9 MB total
    char* wsb = (char*)d_ws;
    __hip_bfloat16* xb    = (__hip_bfloat16*)wsb;                 // 6,553,600 B
    __hip_bfloat16* wqkv  = (__hip_bfloat16*)(wsb + 6553600);     // 1,572,864 B
    __hip_bfloat16* wproj = (__hip_bfloat16*)(wsb + 8126464);     //   524,288 B
    __hip_bfloat16* qkv   = (__hip_bfloat16*)(wsb + 8650752);     // 19,660,800 B
    __hip_bfloat16* aout  = (__hip_bfloat16*)(wsb + 28311552);    // 6,553,600 B

    dim3 blk(256);
    cast_f32_bf16<<<dim3((unsigned)(n_x / 4 / 256)), blk, 0, stream>>>(x, xb, (int)(n_x / 4));
    cast_f32_bf16<<<dim3((unsigned)(n_wqkv / 4 / 256)), blk, 0, stream>>>(qkv_w, wqkv, (int)(n_wqkv / 4));
    cast_f32_bf16<<<dim3((unsigned)(n_wproj / 4 / 256)), blk, 0, stream>>>(proj_w, wproj, (int)(n_wproj / 4));

    gemm_bt_bias<__hip_bfloat16><<<dim3((3 * DIM) / 256, NPIX / 64), blk, 0, stream>>>(
        xb, wqkv, qkv_b, qkv, NPIX, 3 * DIM, DIM);

    natten_tiled<<<dim3(100, 8), blk, 0, stream>>>(qkv, rpb, aout);

    gemm_bt_bias<float><<<dim3(DIM / 256, NPIX / 64), blk, 0, stream>>>(
        aout, wproj, proj_b, out, NPIX, DIM, DIM);
}

// Round 6
// 149.282 us; speedup vs baseline: 2.5398x; 1.2441x over previous
//
#include <hip/hip_runtime.h>
#include <hip/hip_bf16.h>

// Nat2D neighborhood attention, MI355X gfx950.
// Device ABI: f32 inputs, f32 output. bf16 MFMA for GEMMs, bf16 qkv intermediate.
// Pipeline: [cast3 x,Wqkv,Wproj -> bf16] -> [gemm_lds QKV -> bf16 qkv] ->
//           [natten_tiled: 8x8 pixel tile x head, K/V halo in LDS] ->
//           [gemm_lds proj -> f32 out]

typedef __attribute__((ext_vector_type(4))) float f32x4;
typedef __attribute__((ext_vector_type(8))) short bf16x8;
typedef __attribute__((ext_vector_type(4))) short s16x4;

#define HEADS 8
#define HEAD_DIM 64
#define DIM 512
#define KW 7
#define HH 80
#define WW 80
#define NPIX (HH * WW)

__device__ inline unsigned short f2bf(float f) {
    union { __hip_bfloat16 b; unsigned short u; } cvt;
    cvt.b = __float2bfloat16(f);
    return cvt.u;
}
__device__ inline float bf2f(short s) {
    union { float f; unsigned u; } c;
    c.u = ((unsigned)(unsigned short)s) << 16;
    return c.f;
}

__device__ inline void storeC(float* p, float v) { *p = v; }
__device__ inline void storeC(__hip_bfloat16* p, float v) { *p = __float2bfloat16(v); }

// async global->LDS, 16B per lane. LDS dest must be linear in lane order.
__device__ inline void g2l16(const void* g, void* l) {
    __builtin_amdgcn_global_load_lds(
        (const __attribute__((address_space(1))) unsigned int*)g,
        (__attribute__((address_space(3))) unsigned int*)l,
        16, 0, 0);
}

// Fused f32 -> bf16 cast for three arrays (x, qkv_w, proj_w). n*4 = elems/4.
__global__ __launch_bounds__(256) void cast3_f32_bf16(
    const float* __restrict__ a, short* __restrict__ oa, int na4,
    const float* __restrict__ b, short* __restrict__ ob, int nb4,
    const float* __restrict__ c, short* __restrict__ oc, int nc4)
{
    int i = blockIdx.x * 256 + threadIdx.x;
    const float* src; short* dst; int idx;
    if (i < na4) { src = a; dst = oa; idx = i; }
    else if (i < na4 + nb4) { src = b; dst = ob; idx = i - na4; }
    else if (i < na4 + nb4 + nc4) { src = c; dst = oc; idx = i - na4 - nb4; }
    else return;
    f32x4 v = reinterpret_cast<const f32x4*>(src)[idx];
    s16x4 r;
#pragma unroll
    for (int j = 0; j < 4; ++j) r[j] = (short)f2bf(v[j]);
    reinterpret_cast<s16x4*>(dst)[idx] = r;
}

// C[m,n] = sum_k A[m,k] * W[n,k] + bias[n]   (A @ W^T + b)
// A: M x K bf16, W: N x K bf16, both row-major. 128x128 tile, BK=64,
// 4 waves in 2x2 quadrants, double-buffered LDS via global_load_lds(16B),
// XOR-swizzle (chunk ^= row&7) applied on SOURCE addr + ds_read (rule #21).
// Requires M%128==0, N%128==0, K%64==0.
template <typename CT>
__global__ __launch_bounds__(256) void gemm_lds(
    const __hip_bfloat16* __restrict__ A,
    const __hip_bfloat16* __restrict__ W,
    const float* __restrict__ bias,
    CT* __restrict__ C,
    int M, int N, int K)
{
    // [buf][A=0/B=1][row 0..127][k 0..63] bf16  = 64 KiB
    __shared__ short lds[2][2][128][64];

    const int lane = threadIdx.x & 63;
    const int wv = threadIdx.x >> 6;
    const int wr = wv >> 1;        // wave row quadrant (0/1)
    const int wc = wv & 1;         // wave col quadrant (0/1)
    const int r0 = blockIdx.y * 128;
    const int c0 = blockIdx.x * 128;
    const int rf = lane & 15;
    const int kg = lane >> 4;

    const int NT = K >> 6;         // K-steps of 64

    // stage one 128x64 tile (A or W panel) into lds buffer `dst`
    auto stage = [&](const __hip_bfloat16* src, int rowbase, int kb, short* dst) {
#pragma unroll
        for (int q = 0; q < 4; ++q) {
            const int L = wv * 256 + q * 64 + lane;   // 16B-slot index 0..1023
            const int r = L >> 3;
            const int cs = (L & 7) ^ (r & 7);         // inverse-swizzled source chunk
            g2l16(src + (size_t)(rowbase + r) * K + kb + cs * 8, dst + (size_t)L * 8);
        }
    };
    // read logical chunk `ch` (8 bf16) of row `row` from a staged panel
    auto frag = [&](const short* base, int row, int ch) -> bf16x8 {
        return *reinterpret_cast<const bf16x8*>(base + row * 64 + ((ch ^ (row & 7)) << 3));
    };

    f32x4 acc[4][4] = {};

    stage(A, r0, 0, &lds[0][0][0][0]);
    stage(W, c0, 0, &lds[0][1][0][0]);
    __syncthreads();

    int cur = 0;
    for (int t = 0; t < NT; ++t) {
        if (t + 1 < NT) {
            stage(A, r0, (t + 1) * 64, &lds[cur ^ 1][0][0][0]);
            stage(W, c0, (t + 1) * 64, &lds[cur ^ 1][1][0][0]);
        }
        const short* la = &lds[cur][0][0][0];
        const short* lb = &lds[cur][1][0][0];
#pragma unroll
        for (int ks = 0; ks < 2; ++ks) {
            bf16x8 af[4], bfr[4];
#pragma unroll
            for (int i = 0; i < 4; ++i)
                af[i] = frag(la, wr * 64 + i * 16 + rf, ks * 4 + kg);
#pragma unroll
            for (int j = 0; j < 4; ++j)
                bfr[j] = frag(lb, wc * 64 + j * 16 + rf, ks * 4 + kg);
#pragma unroll
            for (int i = 0; i < 4; ++i)
#pragma unroll
                for (int j = 0; j < 4; ++j)
                    acc[i][j] = __builtin_amdgcn_mfma_f32_16x16x32_bf16(af[i], bfr[j], acc[i][j], 0, 0, 0);
        }
        __syncthreads();
        cur ^= 1;
    }

    // C/D layout: col = lane&15, row = (lane>>4)*4 + reg  [m89-verified]
#pragma unroll
    for (int j = 0; j < 4; ++j) {
        const int col = c0 + wc * 64 + j * 16 + rf;
        const float bcol = bias[col];
#pragma unroll
        for (int i = 0; i < 4; ++i) {
#pragma unroll
            for (int r = 0; r < 4; ++r) {
                const int row = r0 + wr * 64 + i * 16 + kg * 4 + r;
                storeC(C + (size_t)row * N + col, acc[i][j][r] + bcol);
            }
        }
    }
}

// Tiled natten: block = (8x8 pixel tile) x (one head). 256 threads = 4 waves.
// Stage K/V halo (14x14 rows x 64 dims, bf16, stride 72) + rpb slice in LDS.
// Thread (p, g): pixel p (0..63), dim-quarter g (0..3) -> dims g*16..g*16+15.
__global__ __launch_bounds__(256) void natten_tiled(
    const __hip_bfloat16* __restrict__ qkv,
    const float* __restrict__ rpb,
    __hip_bfloat16* __restrict__ aout)
{
    __shared__ short sK[196][72];
    __shared__ short sV[196][72];
    __shared__ float sW[64][52];
    __shared__ float sB[169];

    const int tid = threadIdx.x;
    const int h = blockIdx.y;
    const int ti = blockIdx.x / 10;
    const int tj = blockIdx.x - ti * 10;
    const int R0 = ti * 8 - 3;
    const int C0 = tj * 8 - 3;

    if (tid < 169) sB[tid] = rpb[h * 169 + tid];

#pragma unroll
    for (int it = 0; it < 7; ++it) {
        const int task = it * 256 + tid;
        if (task < 1568) {
            const int slot = task >> 3;
            const int ch = task & 7;
            const int r = slot / 14;
            const int c = slot - r * 14;
            int gi = R0 + r; gi = gi < 0 ? 0 : (gi > 79 ? 79 : gi);
            int gj = C0 + c; gj = gj < 0 ? 0 : (gj > 79 ? 79 : gj);
            const __hip_bfloat16* src =
                qkv + ((size_t)(gi * WW + gj) * 1536 + 512 + h * 64 + ch * 8);
            bf16x8 kv = *reinterpret_cast<const bf16x8*>(src);
            bf16x8 vv = *reinterpret_cast<const bf16x8*>(src + 512);
            *reinterpret_cast<bf16x8*>(&sK[slot][ch * 8]) = kv;
            *reinterpret_cast<bf16x8*>(&sV[slot][ch * 8]) = vv;
        }
    }
    __syncthreads();

    const int lane = tid & 63;
    const int wv = tid >> 6;
    const int p = wv * 16 + (lane >> 2);
    const int g = lane & 3;
    const int pi_l = p >> 3, pj_l = p & 7;
    const int pi = ti * 8 + pi_l, pj = tj * 8 + pj_l;
    int si = pi - 3; si = si < 0 ? 0 : (si > (HH - KW) ? (HH - KW) : si);
    int sj = pj - 3; sj = sj < 0 ? 0 : (sj > (WW - KW) ? (WW - KW) : sj);
    const int si_l = si - R0;
    const int sj_l = sj - C0;
    const int oh = si - pi + 6;
    const int ow = sj - pj + 6;

    float qf[16];
    {
        const __hip_bfloat16* qsrc =
            qkv + ((size_t)(pi * WW + pj) * 1536 + h * 64 + g * 16);
        bf16x8 q0 = *reinterpret_cast<const bf16x8*>(qsrc);
        bf16x8 q1 = *reinterpret_cast<const bf16x8*>(qsrc + 8);
#pragma unroll
        for (int j = 0; j < 8; ++j) {
            qf[j] = 0.125f * bf2f(q0[j]);
            qf[8 + j] = 0.125f * bf2f(q1[j]);
        }
    }

    // Phase 1: 49 logits per pixel
    for (int a = 0; a < KW; ++a) {
        const int rbase = (si_l + a) * 14 + sj_l;
        const float* brow = &sB[(oh + a) * 13 + ow];
#pragma unroll
        for (int c = 0; c < KW; ++c) {
            const int slot = rbase + c;
            bf16x8 k0 = *reinterpret_cast<const bf16x8*>(&sK[slot][g * 16]);
            bf16x8 k1 = *reinterpret_cast<const bf16x8*>(&sK[slot][g * 16 + 8]);
            float d = 0.f;
#pragma unroll
            for (int j = 0; j < 8; ++j) d += qf[j] * bf2f(k0[j]);
#pragma unroll
            for (int j = 0; j < 8; ++j) d += qf[8 + j] * bf2f(k1[j]);
            d += __shfl_xor(d, 1, 64);
            d += __shfl_xor(d, 2, 64);
            if (g == 0) sW[p][a * KW + c] = d + brow[c];
        }
    }

    // Phase 2: softmax over 49 (redundant across g-lanes; g==0 writes exp)
    float m = -1e30f;
    for (int i = 0; i < 49; ++i) m = fmaxf(m, sW[p][i]);
    float s = 0.f;
    for (int i = 0; i < 49; ++i) {
        const float e = __expf(sW[p][i] - m);
        s += e;
        if (g == 0) sW[p][i] = e;
    }
    const float rs = 1.0f / s;

    // Phase 3
    float o[16];
#pragma unroll
    for (int j = 0; j < 16; ++j) o[j] = 0.f;
    for (int a = 0; a < KW; ++a) {
        const int rbase = (si_l + a) * 14 + sj_l;
#pragma unroll
        for (int c = 0; c < KW; ++c) {
            const int slot = rbase + c;
            const float w = sW[p][a * KW + c];
            bf16x8 v0 = *reinterpret_cast<const bf16x8*>(&sV[slot][g * 16]);
            bf16x8 v1 = *reinterpret_cast<const bf16x8*>(&sV[slot][g * 16 + 8]);
#pragma unroll
            for (int j = 0; j < 8; ++j) o[j] += w * bf2f(v0[j]);
#pragma unroll
            for (int j = 0; j < 8; ++j) o[8 + j] += w * bf2f(v1[j]);
        }
    }

    bf16x8 r0v, r1v;
#pragma unroll
    for (int j = 0; j < 8; ++j) {
        r0v[j] = (short)f2bf(o[j] * rs);
        r1v[j] = (short)f2bf(o[8 + j] * rs);
    }
    __hip_bfloat16* dst = aout + ((size_t)(pi * WW + pj) * 512 + h * 64 + g * 16);
    *reinterpret_cast<bf16x8*>(dst) = r0v;
    *reinterpret_cast<bf16x8*>(dst + 8) = r1v;
}

extern "C" void kernel_launch(void* const* d_in, const int* in_sizes, int n_in,
                              void* d_out, int out_size, void* d_ws, size_t ws_size,
                              hipStream_t stream) {
    const float* x      = (const float*)d_in[0];
    const float* qkv_w  = (const float*)d_in[1];
    const float* qkv_b  = (const float*)d_in[2];
    const float* rpb    = (const float*)d_in[3];
    const float* proj_w = (const float*)d_in[4];
    const float* proj_b = (const float*)d_in[5];
    float* out = (float*)d_out;

    // ws layout (all bf16): xb | wqkv | wproj | qkv | aout  = 34.9 MB total
    char* wsb = (char*)d_ws;
    __hip_bfloat16* xb    = (__hip_bfloat16*)wsb;                 // 6,553,600 B
    __hip_bfloat16* wqkv  = (__hip_bfloat16*)(wsb + 6553600);     // 1,572,864 B
    __hip_bfloat16* wproj = (__hip_bfloat16*)(wsb + 8126464);     //   524,288 B
    __hip_bfloat16* qkv   = (__hip_bfloat16*)(wsb + 8650752);     // 19,660,800 B
    __hip_bfloat16* aout  = (__hip_bfloat16*)(wsb + 28311552);    // 6,553,600 B

    dim3 blk(256);
    // fused casts: x (819200 x4), qkv_w (196608 x4), proj_w (65536 x4)
    cast3_f32_bf16<<<dim3((819200 + 196608 + 65536 + 255) / 256), blk, 0, stream>>>(
        x, (short*)xb, 819200, qkv_w, (short*)wqkv, 196608, proj_w, (short*)wproj, 65536);

    gemm_lds<__hip_bfloat16><<<dim3((3 * DIM) / 128, NPIX / 128), blk, 0, stream>>>(
        xb, wqkv, qkv_b, qkv, NPIX, 3 * DIM, DIM);

    natten_tiled<<<dim3(100, 8), blk, 0, stream>>>(qkv, rpb, aout);

    gemm_lds<float><<<dim3(DIM / 128, NPIX / 128), blk, 0, stream>>>(
        aout, wproj, proj_b, out, NPIX, DIM, DIM);
}